// Round 1
// baseline (227.472 us; speedup 1.0000x reference)
//
#include <hip/hip_runtime.h>

// CSConv2D: per-pixel kernel selection from a 25-entry 5x5 bank, depthwise,
// 'same' zero pad. B=8, C=96, H=W=192, fp32.
//
// R4 structure:
//  - Vertical register blocking kept from R2/R3: each thread owns 4 output
//    rows of one column; weights for its 4 buckets live in 100 VGPRs,
//    gathered once per block (channel-invariant).
//  - Staging rewritten to __builtin_amdgcn_global_load_lds width=16:
//    LDS row re-padded to 200 floats (left pad 4 -> 16B-aligned dest, data
//    in cols 4..195). One wave-op stages one 192-float row (48 lanes x 16B).
//    Kills all staging registers and ds_write traffic (fixes suspected VGPR
//    spill at the launch_bounds(384,3) cap of 168).
//  - 2 channels per phase, 4 LDS slabs (2 phases x 2 channels), 12 barriers
//    instead of 24. Raw s_barrier + counted "s_waitcnt vmcnt(8)": per phase
//    program order is 4 async loads then 8 stores, so vmcnt(8) retires
//    exactly the loads and never waits on output stores (no full drain).
//  - Halo cols (0..3,196..199) and out-of-image rows are zeroed ONCE and
//    persist: async copies only write cols 4..195 of in-bounds rows.

#define KS 5
#define NB 25
#define HALO 2
#define TH 8                     // output rows per block
#define RPT 4                    // output rows per thread
#define WID 192
#define HEI 192
#define CH 96
#define NBATCH 8
#define LPAD 4                   // left pad so row data start is 16B-aligned
#define LROW (LPAD + WID + LPAD) // 200 floats per LDS row
#define LH (TH + 2 * HALO)       // 12 staged rows
#define CSPLIT 4
#define CPB (CH / CSPLIT)        // 24 channels per block
#define NTHREADS (WID * (TH / RPT))  // 384 threads = 6 waves
#define HW ((size_t)HEI * WID)

static_assert(CPB % 2 == 0, "channel loop processes channel pairs");

__device__ __forceinline__ void async16(void* lds, const void* g) {
    // Direct global->LDS copy, 16B per lane. LDS dest is wave-uniform base +
    // lane*16 (hardware semantics); we pass the uniform row base.
    __builtin_amdgcn_global_load_lds(
        (const __attribute__((address_space(1))) void*)g,
        (__attribute__((address_space(3))) void*)lds, 16, 0, 0);
}

__global__ __launch_bounds__(NTHREADS, 3) void csconv_kernel(
    const float* __restrict__ in, const float* __restrict__ bank,
    const int* __restrict__ buckets, float* __restrict__ out)
{
    __shared__ float sb[NB * KS * KS];                    // 2.5 KB kernel bank
    __shared__ __align__(16) float sin_[2][2][LH][LROW];  // 37.5 KB: 2 bufs x 2 ch

    const int tid  = threadIdx.x;
    const int wcol = tid % WID;     // 0..191
    const int ty   = tid / WID;     // 0..1
    const int lane = tid & 63;
    const int wv   = tid >> 6;      // wave id 0..5
    const int cg   = blockIdx.x;    // channel group 0..3
    const int ht   = blockIdx.y;    // row tile 0..23
    const int b    = blockIdx.z;    // batch 0..7
    const int h0   = ht * TH;
    const int r0   = h0 + ty * RPT;

    const int c0 = cg * CPB;
    const float* inb  = in  + (size_t)(b * CH + c0) * HW;
    float*       outb = out + (size_t)(b * CH + c0) * HW;

    // --- one-time LDS init ---------------------------------------------
    // Kernel bank (625 floats > 384 threads: must be strided).
    for (int t = tid; t < NB * KS * KS; t += NTHREADS) sb[t] = bank[t];

    // Zero halo columns 0..3 and 196..199 of all 4 slabs (one write/thread:
    // 4 slabs * 12 rows * 8 cols = 384). Persist: staging writes cols 4..195.
    {
        const int s = tid / 96, rem = tid % 96;
        const int r = rem / 8, p = rem % 8;
        const int col = (p < 4) ? p : (WID + p);   // 0..3, 196..199
        sin_[s >> 1][s & 1][r][col] = 0.0f;
    }
    // Zero out-of-image rows for edge tiles; staging skips them so the
    // zeros persist for every channel.
    if (h0 - HALO < 0) {
        for (int t = tid; t < 4 * 2 * LROW; t += NTHREADS) {
            const int s = t / (2 * LROW), rem = t % (2 * LROW);
            sin_[s >> 1][s & 1][rem / LROW][rem % LROW] = 0.0f;
        }
    }
    if (h0 + TH + HALO > HEI) {
        for (int t = tid; t < 4 * 2 * LROW; t += NTHREADS) {
            const int s = t / (2 * LROW), rem = t % (2 * LROW);
            sin_[s >> 1][s & 1][LH - 2 + rem / LROW][rem % LROW] = 0.0f;
        }
    }

    // Prologue: async-stage channels 0,1 into buffer 0. Wave wv stages rows
    // 2wv, 2wv+1 of each slab; 48 lanes x 16B cover one 192-float row.
#pragma unroll
    for (int s = 0; s < 2; ++s)
#pragma unroll
        for (int k = 0; k < 2; ++k) {
            const int rr = 2 * wv + k;
            const int hg = h0 - HALO + rr;
            if (hg >= 0 && hg < HEI && lane < 48)
                async16(&sin_[0][s][rr][LPAD],
                        inb + (size_t)s * HW + (size_t)hg * WID + lane * 4);
        }

    __syncthreads();   // full drain once: bank, zeros, prologue copies

    // --- per-pixel weight gather (channel-invariant, once per block) ----
    float wreg[RPT][NB];
#pragma unroll
    for (int r = 0; r < RPT; ++r) {
        const int bkt = buckets[(b * HEI + r0 + r) * WID + wcol];
#pragma unroll
        for (int t = 0; t < NB; ++t) wreg[r][t] = sb[bkt * (KS * KS) + t];
    }

    const int ty4 = ty * RPT;

    auto conv_store = [&](int cur, int slab, int cidx) {
        float acc[RPT] = {0.0f, 0.0f, 0.0f, 0.0f};
#pragma unroll
        for (int i = 0; i < TH; ++i) {
            // staged row ty4+i = global row r0-2+i; window cols wcol+2..wcol+6
            const float* rowp = &sin_[cur][slab][ty4 + i][wcol + (LPAD - HALO)];
            const float x0 = rowp[0], x1 = rowp[1], x2 = rowp[2],
                        x3 = rowp[3], x4 = rowp[4];
#pragma unroll
            for (int r = 0; r < RPT; ++r) {
                const int ki = i - r;
                if (ki >= 0 && ki < KS) {   // compile-time after unroll
                    const float* w = &wreg[r][ki * KS];
                    acc[r] += x0 * w[0] + x1 * w[1] + x2 * w[2]
                            + x3 * w[3] + x4 * w[4];
                }
            }
        }
#pragma unroll
        for (int r = 0; r < RPT; ++r)
            outb[(size_t)cidx * HW + (size_t)(r0 + r) * WID + wcol] = acc[r];
    };

    // --- main loop: 12 phases of 2 channels --------------------------------
    for (int c = 0; c < CPB; c += 2) {
        const int cur = (c >> 1) & 1;
        const bool has_next = (c + 2 < CPB);

        if (has_next) {
            const int nxt = cur ^ 1;
#pragma unroll
            for (int s = 0; s < 2; ++s)
#pragma unroll
                for (int k = 0; k < 2; ++k) {
                    const int rr = 2 * wv + k;
                    const int hg = h0 - HALO + rr;
                    if (hg >= 0 && hg < HEI && lane < 48)
                        async16(&sin_[nxt][s][rr][LPAD],
                                inb + (size_t)(c + 2 + s) * HW
                                    + (size_t)hg * WID + lane * 4);
                }
        }

        conv_store(cur, 0, c);
        conv_store(cur, 1, c + 1);

        if (has_next) {
            // Program order this phase: 4 async loads, then 8 stores.
            // vmcnt(8) retires (in-order) everything older than the 8 newest
            // VMEM ops -> exactly the loads; stores stay in flight.
            asm volatile("s_waitcnt vmcnt(8)" ::: "memory");
            __builtin_amdgcn_s_barrier();
            asm volatile("" ::: "memory");
        }
    }
}

extern "C" void kernel_launch(void* const* d_in, const int* in_sizes, int n_in,
                              void* d_out, int out_size, void* d_ws, size_t ws_size,
                              hipStream_t stream) {
    const float* in      = (const float*)d_in[0];
    const float* bank    = (const float*)d_in[1];
    const int*   buckets = (const int*)d_in[2];
    float*       out     = (float*)d_out;
    dim3 grid(CSPLIT, HEI / TH, NBATCH);
    csconv_kernel<<<grid, NTHREADS, 0, stream>>>(in, bank, buckets, out);
}

// Round 2
// 226.744 us; speedup vs baseline: 1.0032x; 1.0032x over previous
//
#include <hip/hip_runtime.h>

// CSConv2D: per-pixel kernel selection from a 25-entry 5x5 bank, depthwise,
// 'same' zero pad. B=8, C=96, H=W=192, fp32.
//
// R5 = R4 + weight-register pinning.
// R4 counters: dur 98.9us, VGPR_Count=80, VALUBusy 27%, HBM 25%, 0 bank
// conflicts. 80 VGPRs cannot hold the 100-float wreg cache -> the compiler
// demoted it (scratch or per-use LDS re-reads of sb[]), making every FMA
// weight operand a memory access: ~280 LDS ops/thread/phase * 18 waves/CU
// * ~4cyc ~= 100us, matching the measurement. The empty asm "+v" per element
// forces each gathered weight into a real VGPR (opaque def: cannot be
// rematerialized from sb or left in scratch). 100 pinned + ~40 working ~=
// 140 < 168 cap from __launch_bounds__(384,3), so no spill.
//
// R4 structure (kept verbatim):
//  - Vertical register blocking: thread owns 4 output rows of one column.
//  - global_load_lds width=16 staging, LDS rows padded to 200 floats
//    (left pad 4 -> 16B-aligned dest; data in cols 4..195).
//  - 2 channels per phase, 4 LDS slabs, 12 barriers; counted
//    s_waitcnt vmcnt(8) before s_barrier (waits loads, not output stores).
//  - Halo cols / OOB rows zeroed once, persist across phases.

#define KS 5
#define NB 25
#define HALO 2
#define TH 8                     // output rows per block
#define RPT 4                    // output rows per thread
#define WID 192
#define HEI 192
#define CH 96
#define NBATCH 8
#define LPAD 4                   // left pad so row data start is 16B-aligned
#define LROW (LPAD + WID + LPAD) // 200 floats per LDS row
#define LH (TH + 2 * HALO)       // 12 staged rows
#define CSPLIT 4
#define CPB (CH / CSPLIT)        // 24 channels per block
#define NTHREADS (WID * (TH / RPT))  // 384 threads = 6 waves
#define HW ((size_t)HEI * WID)

static_assert(CPB % 2 == 0, "channel loop processes channel pairs");

__device__ __forceinline__ void async16(void* lds, const void* g) {
    // Direct global->LDS copy, 16B per lane. LDS dest is wave-uniform base +
    // lane*16 (hardware semantics); we pass the uniform row base.
    __builtin_amdgcn_global_load_lds(
        (const __attribute__((address_space(1))) void*)g,
        (__attribute__((address_space(3))) void*)lds, 16, 0, 0);
}

__global__ __launch_bounds__(NTHREADS, 3) void csconv_kernel(
    const float* __restrict__ in, const float* __restrict__ bank,
    const int* __restrict__ buckets, float* __restrict__ out)
{
    __shared__ float sb[NB * KS * KS];                    // 2.5 KB kernel bank
    __shared__ __align__(16) float sin_[2][2][LH][LROW];  // 37.5 KB: 2 bufs x 2 ch

    const int tid  = threadIdx.x;
    const int wcol = tid % WID;     // 0..191
    const int ty   = tid / WID;     // 0..1
    const int lane = tid & 63;
    const int wv   = tid >> 6;      // wave id 0..5
    const int cg   = blockIdx.x;    // channel group 0..3
    const int ht   = blockIdx.y;    // row tile 0..23
    const int b    = blockIdx.z;    // batch 0..7
    const int h0   = ht * TH;
    const int r0   = h0 + ty * RPT;

    const int c0 = cg * CPB;
    const float* inb  = in  + (size_t)(b * CH + c0) * HW;
    float*       outb = out + (size_t)(b * CH + c0) * HW;

    // --- one-time LDS init ---------------------------------------------
    // Kernel bank (625 floats > 384 threads: must be strided).
    for (int t = tid; t < NB * KS * KS; t += NTHREADS) sb[t] = bank[t];

    // Zero halo columns 0..3 and 196..199 of all 4 slabs (one write/thread:
    // 4 slabs * 12 rows * 8 cols = 384). Persist: staging writes cols 4..195.
    {
        const int s = tid / 96, rem = tid % 96;
        const int r = rem / 8, p = rem % 8;
        const int col = (p < 4) ? p : (WID + p);   // 0..3, 196..199
        sin_[s >> 1][s & 1][r][col] = 0.0f;
    }
    // Zero out-of-image rows for edge tiles; staging skips them so the
    // zeros persist for every channel.
    if (h0 - HALO < 0) {
        for (int t = tid; t < 4 * 2 * LROW; t += NTHREADS) {
            const int s = t / (2 * LROW), rem = t % (2 * LROW);
            sin_[s >> 1][s & 1][rem / LROW][rem % LROW] = 0.0f;
        }
    }
    if (h0 + TH + HALO > HEI) {
        for (int t = tid; t < 4 * 2 * LROW; t += NTHREADS) {
            const int s = t / (2 * LROW), rem = t % (2 * LROW);
            sin_[s >> 1][s & 1][LH - 2 + rem / LROW][rem % LROW] = 0.0f;
        }
    }

    // Prologue: async-stage channels 0,1 into buffer 0. Wave wv stages rows
    // 2wv, 2wv+1 of each slab; 48 lanes x 16B cover one 192-float row.
#pragma unroll
    for (int s = 0; s < 2; ++s)
#pragma unroll
        for (int k = 0; k < 2; ++k) {
            const int rr = 2 * wv + k;
            const int hg = h0 - HALO + rr;
            if (hg >= 0 && hg < HEI && lane < 48)
                async16(&sin_[0][s][rr][LPAD],
                        inb + (size_t)s * HW + (size_t)hg * WID + lane * 4);
        }

    __syncthreads();   // full drain once: bank, zeros, prologue copies

    // --- per-pixel weight gather (channel-invariant, once per block) ----
    float wreg[RPT][NB];
#pragma unroll
    for (int r = 0; r < RPT; ++r) {
        const int bkt = buckets[(b * HEI + r0 + r) * WID + wcol];
#pragma unroll
        for (int t = 0; t < NB; ++t) wreg[r][t] = sb[bkt * (KS * KS) + t];
    }
    // Pin all 100 weights into VGPRs. The empty asm is an opaque def: the
    // value now flows from a register-constrained asm result, so the
    // compiler can neither rematerialize it from sb[] inside the loop nor
    // leave the array in scratch. (R4's VGPR_Count=80 proves it demoted.)
#pragma unroll
    for (int r = 0; r < RPT; ++r)
#pragma unroll
        for (int t = 0; t < NB; ++t)
            asm volatile("" : "+v"(wreg[r][t]));

    const int ty4 = ty * RPT;

    auto conv_store = [&](int cur, int slab, int cidx) {
        float acc[RPT] = {0.0f, 0.0f, 0.0f, 0.0f};
#pragma unroll
        for (int i = 0; i < TH; ++i) {
            // staged row ty4+i = global row r0-2+i; window cols wcol+2..wcol+6
            const float* rowp = &sin_[cur][slab][ty4 + i][wcol + (LPAD - HALO)];
            const float x0 = rowp[0], x1 = rowp[1], x2 = rowp[2],
                        x3 = rowp[3], x4 = rowp[4];
#pragma unroll
            for (int r = 0; r < RPT; ++r) {
                const int ki = i - r;
                if (ki >= 0 && ki < KS) {   // compile-time after unroll
                    const float* w = &wreg[r][ki * KS];
                    acc[r] += x0 * w[0] + x1 * w[1] + x2 * w[2]
                            + x3 * w[3] + x4 * w[4];
                }
            }
        }
#pragma unroll
        for (int r = 0; r < RPT; ++r)
            outb[(size_t)cidx * HW + (size_t)(r0 + r) * WID + wcol] = acc[r];
    };

    // --- main loop: 12 phases of 2 channels --------------------------------
    for (int c = 0; c < CPB; c += 2) {
        const int cur = (c >> 1) & 1;
        const bool has_next = (c + 2 < CPB);

        if (has_next) {
            const int nxt = cur ^ 1;
#pragma unroll
            for (int s = 0; s < 2; ++s)
#pragma unroll
                for (int k = 0; k < 2; ++k) {
                    const int rr = 2 * wv + k;
                    const int hg = h0 - HALO + rr;
                    if (hg >= 0 && hg < HEI && lane < 48)
                        async16(&sin_[nxt][s][rr][LPAD],
                                inb + (size_t)(c + 2 + s) * HW
                                    + (size_t)hg * WID + lane * 4);
                }
        }

        conv_store(cur, 0, c);
        conv_store(cur, 1, c + 1);

        if (has_next) {
            // Program order this phase: 4 async loads, then 8 stores.
            // vmcnt(8) retires (in-order) everything older than the 8 newest
            // VMEM ops -> exactly the loads; stores stay in flight.
            asm volatile("s_waitcnt vmcnt(8)" ::: "memory");
            __builtin_amdgcn_s_barrier();
            asm volatile("" ::: "memory");
        }
    }
}

extern "C" void kernel_launch(void* const* d_in, const int* in_sizes, int n_in,
                              void* d_out, int out_size, void* d_ws, size_t ws_size,
                              hipStream_t stream) {
    const float* in      = (const float*)d_in[0];
    const float* bank    = (const float*)d_in[1];
    const int*   buckets = (const int*)d_in[2];
    float*       out     = (float*)d_out;
    dim3 grid(CSPLIT, HEI / TH, NBATCH);
    csconv_kernel<<<grid, NTHREADS, 0, stream>>>(in, bank, buckets, out);
}